// Round 1
// baseline (334.559 us; speedup 1.0000x reference)
//
#include <hip/hip_runtime.h>
#include <math.h>

// ---------------- problem constants ----------------
#define NPIX 128
#define MASKM 2548
#define NPAD 2560          // padded q count (20*128)
#define MG   6912          // GEMM M = 9 taps * 768
#define KD   768

typedef __attribute__((ext_vector_type(8))) short bf16x8;
typedef __attribute__((ext_vector_type(4))) float f32x4;
typedef __attribute__((ext_vector_type(8))) unsigned short ushort8;

// ---------------- workspace layout ----------------
static constexpr size_t OFF_QI   = 0;
static constexpr size_t OFF_QJ   = OFF_QI + NPAD * 4;
static constexpr size_t OFF_QIDX = OFF_QJ + NPAD * 4;
static constexpr size_t OFF_APIX = OFF_QIDX + 16384 * 4;
static constexpr size_t OFF_START= OFF_APIX + 16384 * 4;
static constexpr size_t OFF_PART = OFF_START + 128 * 4;
static constexpr size_t OFF_STAT = OFF_PART + 512 * 8 * 8;
static constexpr size_t OFF_SC   = OFF_STAT + 256;
static constexpr size_t OFF_HM   = OFF_SC + NPAD * 4;
static constexpr size_t OFF_AH   = OFF_HM + (size_t)MASKM * KD * 4;
static constexpr size_t OFF_AL   = OFF_AH + (size_t)MG * KD * 2;
static constexpr size_t OFF_BH   = OFF_AL + (size_t)MG * KD * 2;
static constexpr size_t OFF_BL   = OFF_BH + (size_t)NPAD * KD * 2;
static constexpr size_t OFF_YT   = OFF_BL + (size_t)NPAD * KD * 2;
// X (7.9MB fp32) aliases the head of Yt (70.8MB): dead before k_gemm writes Yt.
static constexpr size_t OFF_X    = OFF_YT;

// ---------------- bf16 hi/lo split helpers ----------------
__device__ __forceinline__ unsigned short f2bf(float f) {
    unsigned u = __float_as_uint(f);
    u = u + 0x7FFFu + ((u >> 16) & 1u);       // RNE
    return (unsigned short)(u >> 16);
}
__device__ __forceinline__ float bf2f(unsigned short h) {
    return __uint_as_float(((unsigned)h) << 16);
}

// ---------------- mask structure (closed form) ----------------
__device__ __forceinline__ bool mask_allowed(int i, int d) {
    if (d == 0) return true;
    if (d <= 15) return true;
    if (d <= 31) return (d >= 17) && ((d & 1) == 1) && ((i & 1) == 0);
    if (d <= 63) return (d >= 35) && ((d & 3) == 3) && ((i & 3) == 0);
    return (d >= 71) && ((d & 7) == 7) && ((i & 7) == 0);
}
__device__ __forceinline__ bool masked_ij(int i, int j) {
    return (j >= i) && (j < NPIX) && (i >= 0) && mask_allowed(i, j - i);
}

// 1 block x 128: per-row q-offsets only (cheap)
__global__ void k_rowstart(int* startv) {
    __shared__ int cnt[NPIX];
    int i = threadIdx.x;
    int c = 0;
    for (int d = 0; i + d < NPIX; ++d) if (mask_allowed(i, d)) ++c;
    cnt[i] = c;
    __syncthreads();
    if (i == 0) {
        int s = 0;
        for (int r = 0; r < NPIX; ++r) { startv[r] = s; s += cnt[r]; }
    }
}

// 64 blocks x 256: one thread per pixel -> qidx, apix, qi/qj
__global__ void k_fill(const int* __restrict__ startv, int* __restrict__ qi,
                       int* __restrict__ qj, int* __restrict__ qidx,
                       int* __restrict__ apix) {
    int p = blockIdx.x * 256 + threadIdx.x;
    int i = p >> 7, j = p & 127;
    int q = -1;
    if (masked_ij(i, j)) {
        int d = j - i, r = 0;
        for (int dd = 0; dd < d; ++dd) r += mask_allowed(i, dd) ? 1 : 0;
        q = startv[i] + r;
        qi[q] = i; qj[q] = j;
    }
    qidx[p] = q;
    int act = 0;
    #pragma unroll
    for (int dy = -1; dy <= 1; ++dy)
        #pragma unroll
        for (int dx = -1; dx <= 1; ++dx)
            if (masked_ij(i + dy, j + dx)) act = 1;
    apix[p] = act;
}

// ---------------- X[c][q] = max(fea[c, i..j]) via sparse table ----------------
__global__ void k_buildX(const float* __restrict__ fea, const int* __restrict__ qi,
                         const int* __restrict__ qj, float* __restrict__ X) {
    __shared__ float tab[8][NPIX];
    int c = blockIdx.x, t = threadIdx.x;
    tab[0][t]      = fea[c * NPIX + t];
    tab[0][t + 64] = fea[c * NPIX + t + 64];
    __syncthreads();
    for (int l = 1; l < 8; ++l) {
        int half = 1 << (l - 1), full = 1 << l;
        for (int i = t; i < NPIX; i += 64)
            if (i + full <= NPIX) tab[l][i] = fmaxf(tab[l - 1][i], tab[l - 1][i + half]);
        __syncthreads();
    }
    for (int q = t; q < NPAD; q += 64) {
        float v = 0.f;
        if (q < MASKM) {
            int i = qi[q], j = qj[q];
            int len = j - i + 1;
            int l = 31 - __clz(len);
            v = fmaxf(tab[l][i], tab[l][j + 1 - (1 << l)]);
        }
        X[c * NPAD + q] = v;
    }
}

// ---------------- fused reorder+split: w1[co][ci*9+tap] -> Ah/Al[(tap*768+co)][ci] ----------------
__global__ __launch_bounds__(256) void k_prepA(const float* __restrict__ w1,
                                               unsigned short* __restrict__ Ah,
                                               unsigned short* __restrict__ Al) {
    __shared__ float tile[64 * 144];   // [co 64][ci16*9tap = 144]
    int co0 = blockIdx.x * 64, ci0 = blockIdx.y * 64;
    int tid = threadIdx.x;
    for (int s = 0; s < 4; ++s) {
        int cib = ci0 + s * 16;
        __syncthreads();
        for (int idx = tid; idx < 2304; idx += 256) {
            int row = idx / 36, c4 = idx % 36;
            float4 v = *(const float4*)(w1 + (size_t)(co0 + row) * MG + cib * 9 + c4 * 4);
            *(float4*)&tile[row * 144 + c4 * 4] = v;
        }
        __syncthreads();
        for (int idx = tid; idx < 1152; idx += 256) {
            int tap = idx / 128;
            int rem = idx - tap * 128;
            int co = rem >> 1, half = rem & 1;
            ushort8 vh, vl;
            #pragma unroll
            for (int c = 0; c < 8; ++c) {
                float v = tile[co * 144 + (half * 8 + c) * 9 + tap];
                unsigned short hi = f2bf(v);
                vh[c] = hi;
                vl[c] = f2bf(v - bf2f(hi));
            }
            size_t ob = (size_t)(tap * 768 + co0 + co) * KD + cib + half * 8;
            *(ushort8*)(Ah + ob) = vh;
            *(ushort8*)(Al + ob) = vl;
        }
    }
}

// ---------------- transpose + bf16 hi/lo split: src[768][C] -> dst[C][768] ----------------
__global__ void k_trans(const float* __restrict__ src, int C,
                        unsigned short* __restrict__ dh, unsigned short* __restrict__ dl) {
    __shared__ float tile[64][65];
    int c0 = blockIdx.x * 64, k0 = blockIdx.y * 64;
    int t = threadIdx.x;
    int r = t >> 2, cq = (t & 3) << 4;
    const float* s = src + (size_t)(k0 + r) * C + c0 + cq;
    #pragma unroll
    for (int u = 0; u < 16; u += 4) {
        float4 v = *(const float4*)(s + u);
        tile[r][cq + u]     = v.x;
        tile[r][cq + u + 1] = v.y;
        tile[r][cq + u + 2] = v.z;
        tile[r][cq + u + 3] = v.w;
    }
    __syncthreads();
    size_t ob = (size_t)(c0 + r) * KD + k0 + cq;
    #pragma unroll
    for (int u = 0; u < 16; ++u) {
        float v = tile[cq + u][r];
        unsigned short hi = f2bf(v);
        float lo = v - bf2f(hi);
        dh[ob + u] = hi;
        dl[ob + u] = f2bf(lo);
    }
}

// ---------------- bf16x3 MFMA GEMM: Yt[n][m] = sum_k A[m][k] * B[n][k] ----------------
// 3-deep circular LDS pipeline, 4 phases/K-tile, counted vmcnt (never 0 in steady
// state), raw s_barrier + setprio. BM=256 BN=128 BK=32, 512 thr = 8 waves, each
// wave owns a 64x64 output tile (best LDS-bytes/MFMA at this wave count).
// Staging keeps the proven chunk-XOR swizzle (pre-swizzled per-lane global src,
// linear LDS dest) -> SQ_LDS_BANK_CONFLICT == 0 carried over from prior kernel.
#define GB_AH 0
#define GB_AL 16384
#define GB_BH 32768
#define GB_BL 40960
#define GB_SZ 49152        // one K-tile buffer: Ah|Al (256x32) + Bh|Bl (128x32)

__global__ __launch_bounds__(512, 2) void k_gemm(const unsigned short* __restrict__ Ah,
                                                 const unsigned short* __restrict__ Al,
                                                 const unsigned short* __restrict__ Bh,
                                                 const unsigned short* __restrict__ Bl,
                                                 float* __restrict__ Yt) {
    extern __shared__ char sm[];               // 3 * GB_SZ = 144 KB dynamic LDS
    int tid = threadIdx.x;
    int wave = tid >> 6, lane = tid & 63;

    // bijective XCD swizzle for 540 blocks (540 = 8*67+4 -> q=67, r=4; m204 form)
    int bid = (int)blockIdx.x;
    int xcd = bid & 7, loc = bid >> 3;
    int wg = (xcd < 4 ? xcd * 68 : 272 + (xcd - 4) * 67) + loc;
    int by = wg / 20, bx = wg - by * 20;       // 20 N-tiles, 27 M-tiles
    int m0 = by * 256, n0 = bx * 128;

    int wm = (wave & 3) << 6, wn = (wave >> 2) << 6;   // 4M x 2N wave grid
    int r4 = lane >> 2, c4 = lane & 3;
    int fr = lane & 15, fq = lane >> 4;
    int csw = c4 ^ ((r4 >> 1) & 3);                    // staging chunk swizzle
    int fb = (fq ^ ((fr >> 1) & 3)) << 4;              // frag chunk slot (bytes)

    // 6 stage slots per wave: wave-instruction id = wave*6+s over 48 total.
    // ids 0-15: Ah 16-row groups; 16-31: Al; 32-39: Bh; 40-47: Bl.
    const unsigned short* sp[6];
    int so[6];
    #pragma unroll
    for (int s = 0; s < 6; ++s) {
        int id = wave * 6 + s;
        const unsigned short* base;
        int row0, ldso;
        if (id < 16)      { base = Ah; row0 = m0 + id * 16;        ldso = GB_AH + id * 1024; }
        else if (id < 32) { base = Al; row0 = m0 + (id - 16) * 16; ldso = GB_AL + (id - 16) * 1024; }
        else if (id < 40) { base = Bh; row0 = n0 + (id - 32) * 16; ldso = GB_BH + (id - 32) * 1024; }
        else              { base = Bl; row0 = n0 + (id - 40) * 16; ldso = GB_BL + (id - 40) * 1024; }
        sp[s] = base + (size_t)(row0 + r4) * KD + csw * 8;
        so[s] = ldso;
    }

    f32x4 acc[4][4] = {};

    char* B0 = sm;                 // compute buffer (tile t)
    char* B1 = sm + GB_SZ;         // next tile (in flight / ready)
    char* B2 = sm + 2 * GB_SZ;     // staging target (tile t+2); freed at end of t-1

    #define STAGE(s, SB, ks) __builtin_amdgcn_global_load_lds( \
        (const __attribute__((address_space(1))) unsigned int*)(sp[s] + (ks)), \
        (__attribute__((address_space(3))) unsigned int*)((SB) + so[s]), 16, 0, 0)
    #define RD(CB, MOFF, row) (*(const bf16x8*)((CB) + (MOFF) + ((row) << 6) + fb))
    #define TRIPLE(mi, ni, xh, xl, yh, yl) \
        acc[mi][ni] = __builtin_amdgcn_mfma_f32_16x16x32_bf16(xh, yh, acc[mi][ni], 0, 0, 0); \
        acc[mi][ni] = __builtin_amdgcn_mfma_f32_16x16x32_bf16(xh, yl, acc[mi][ni], 0, 0, 0); \
        acc[mi][ni] = __builtin_amdgcn_mfma_f32_16x16x32_bf16(xl, yh, acc[mi][ni], 0, 0, 0);

    // prologue: stage tiles 0 (->B0) and 1 (->B1); wait only for tile 0.
    #pragma unroll
    for (int s = 0; s < 6; ++s) STAGE(s, B0, 0);
    #pragma unroll
    for (int s = 0; s < 6; ++s) STAGE(s, B1, 32);
    asm volatile("s_waitcnt vmcnt(6)" ::: "memory");
    __builtin_amdgcn_s_barrier();

    for (int t = 0; t < 24; ++t) {             // K = 768 = 24 tiles of 32
        int ks = (t + 2) * 32;
        bool stg = (t <= 21);                  // issue tile t+2 while computing t
        bf16x8 a0h, a1h, a0l, a1l, a2h, a3h, a2l, a3l;
        bf16x8 b0h, b1h, b0l, b1l, b2h, b3h, b2l, b3l;

        // ---- phase 0: mi{0,1} x ni{0,1} ----
        a0h = RD(B0, GB_AH, wm + fr);       a1h = RD(B0, GB_AH, wm + 16 + fr);
        a0l = RD(B0, GB_AL, wm + fr);       a1l = RD(B0, GB_AL, wm + 16 + fr);
        b0h = RD(B0, GB_BH, wn + fr);       b1h = RD(B0, GB_BH, wn + 16 + fr);
        b0l = RD(B0, GB_BL, wn + fr);       b1l = RD(B0, GB_BL, wn + 16 + fr);
        if (stg) { STAGE(0, B2, ks); STAGE(1, B2, ks); }
        asm volatile("" ::: "memory");
        __builtin_amdgcn_s_barrier();
        asm volatile("s_waitcnt lgkmcnt(0)" ::: "memory");
        __builtin_amdgcn_s_setprio(1);
        TRIPLE(0, 0, a0h, a0l, b0h, b0l)
        TRIPLE(0, 1, a0h, a0l, b1h, b1l)
        TRIPLE(1, 0, a1h, a1l, b0h, b0l)
        TRIPLE(1, 1, a1h, a1l, b1h, b1l)
        __builtin_amdgcn_s_setprio(0);
        __builtin_amdgcn_s_barrier();

        // ---- phase 1: mi{0,1} x ni{2,3} (reuse a0..a1) ----
        b2h = RD(B0, GB_BH, wn + 32 + fr);  b3h = RD(B0, GB_BH, wn + 48 + fr);
        b2l = RD(B0, GB_BL, wn + 32 + fr);  b3l = RD(B0, GB_BL, wn + 48 + fr);
        if (stg) { STAGE(2, B2, ks); STAGE(3, B2, ks); }
        asm volatile("" ::: "memory");
        __builtin_amdgcn_s_barrier();
        asm volatile("s_waitcnt lgkmcnt(0)" ::: "memory");
        __builtin_amdgcn_s_setprio(1);
        TRIPLE(0, 2, a0h, a0l, b2h, b2l)
        TRIPLE(0, 3, a0h, a0l, b3h, b3l)
        TRIPLE(1, 2, a1h, a1l, b2h, b2l)
        TRIPLE(1, 3, a1h, a1l, b3h, b3l)
        __builtin_amdgcn_s_setprio(0);
        __builtin_amdgcn_s_barrier();

        // ---- phase 2: mi{2,3} x ni{0,1} (reuse b0..b1) ----
        a2h = RD(B0, GB_AH, wm + 32 + fr);  a3h = RD(B0, GB_AH, wm + 48 + fr);
        a2l = RD(B0, GB_AL, wm + 32 + fr);  a3l = RD(B0, GB_AL, wm + 48 + fr);
        if (stg) STAGE(4, B2, ks);
        asm volatile("" ::: "memory");
        __builtin_amdgcn_s_barrier();
        asm volatile("s_waitcnt lgkmcnt(0)" ::: "memory");
        __builtin_amdgcn_s_setprio(1);
        TRIPLE(2, 0, a2h, a2l, b0h, b0l)
        TRIPLE(2, 1, a2h, a2l, b1h, b1l)
        TRIPLE(3, 0, a3h, a3l, b0h, b0l)
        TRIPLE(3, 1, a3h, a3l, b1h, b1l)
        __builtin_amdgcn_s_setprio(0);
        __builtin_amdgcn_s_barrier();

        // ---- phase 3: mi{2,3} x ni{2,3} (all frags live; no LDS reads) ----
        if (stg) STAGE(5, B2, ks);
        asm volatile("" ::: "memory");
        __builtin_amdgcn_s_barrier();
        __builtin_amdgcn_s_setprio(1);
        TRIPLE(2, 2, a2h, a2l, b2h, b2l)
        TRIPLE(2, 3, a2h, a2l, b3h, b3l)
        TRIPLE(3, 2, a3h, a3l, b2h, b2l)
        TRIPLE(3, 3, a3h, a3l, b3h, b3l)
        __builtin_amdgcn_s_setprio(0);
        // end-of-tile gate: tile t+1 (oldest 6 loads) must be resident before
        // any wave reads B1 next iteration; 6 loads of t+2 stay in flight.
        if (t <= 21)      asm volatile("s_waitcnt vmcnt(6)" ::: "memory");
        else if (t == 22) asm volatile("s_waitcnt vmcnt(0)" ::: "memory");
        __builtin_amdgcn_s_barrier();

        char* tmp = B0; B0 = B1; B1 = B2; B2 = tmp;   // rotate circular buffers
    }

    #pragma unroll
    for (int mi = 0; mi < 4; ++mi)
        #pragma unroll
        for (int ni = 0; ni < 4; ++ni) {
            int n = n0 + wn + ni * 16 + fr;
            int m = m0 + wm + mi * 16 + fq * 4;
            *(f32x4*)(Yt + (size_t)n * MG + m) = acc[mi][ni];
        }
    #undef STAGE
    #undef RD
    #undef TRIPLE
}

// ---------------- gather taps -> hm (masked rows) + GN partial sums (active pixels only) ----------------
__global__ __launch_bounds__(256) void k_gather(const float* __restrict__ Yt,
                                                const int* __restrict__ qidx,
                                                const int* __restrict__ apix,
                                                float* __restrict__ hm,
                                                double* __restrict__ part) {
    __shared__ double red1[256 * 4], red2[256 * 4];
    int tid = threadIdx.x;
    int wave = tid >> 6, lane = tid & 63;
    double a1[3] = {0, 0, 0}, a2[3] = {0, 0, 0};
    int gs[3];
    #pragma unroll
    for (int s = 0; s < 3; ++s) gs[s] = (64 * s + lane) / 48;

    for (int it = 0; it < 8; ++it) {
        int p = blockIdx.x * 32 + wave * 8 + it;   // wave-uniform pixel
        if (!apix[p]) continue;
        int y = p >> 7, x = p & 127;
        float4 hv[3] = {};
        #pragma unroll
        for (int tap = 0; tap < 9; ++tap) {
            int i = y + tap / 3 - 1, j = x + tap % 3 - 1;
            if ((unsigned)i < 128u && (unsigned)j < 128u) {
                int q = qidx[i * NPIX + j];
                if (q >= 0) {
                    const float* yr = Yt + (size_t)q * MG + tap * 768 + lane * 4;
                    #pragma unroll
                    for (int s = 0; s < 3; ++s) {
                        float4 v = *(const float4*)(yr + s * 256);
                        hv[s].x += v.x; hv[s].y += v.y; hv[s].z += v.z; hv[s].w += v.w;
                    }
                }
            }
        }
        int qp = qidx[p];
        if (qp >= 0) {
            #pragma unroll
            for (int s = 0; s < 3; ++s)
                *(float4*)(hm + (size_t)qp * KD + s * 256 + lane * 4) = hv[s];
        }
        #pragma unroll
        for (int s = 0; s < 3; ++s) {
            a1[s] += (double)hv[s].x + (double)hv[s].y + (double)hv[s].z + (double)hv[s].w;
            a2[s] += (double)hv[s].x * hv[s].x + (double)hv[s].y * hv[s].y +
                     (double)hv[s].z * hv[s].z + (double)hv[s].w * hv[s].w;
        }
    }
    #pragma unroll
    for (int g = 0; g < 4; ++g) { red1[tid * 4 + g] = 0.0; red2[tid * 4 + g] = 0.0; }
    #pragma unroll
    for (int s = 0; s < 3; ++s) { red1[tid * 4 + gs[s]] = a1[s]; red2[tid * 4 + gs[s]] = a2[s]; }
    __syncthreads();
    if (tid < 4) {
        double s1 = 0.0, s2 = 0.0;
        for (int i = 0; i < 256; ++i) { s1 += red1[i * 4 + tid]; s2 += red2[i * 4 + tid]; }
        part[blockIdx.x * 8 + tid] = s1;
        part[blockIdx.x * 8 + 4 + tid] = s2;
    }
}

__global__ void k_finalize(const double* __restrict__ part, float* __restrict__ stats) {
    int g = threadIdx.x;
    if (g >= 4) return;
    double s1 = 0.0, s2 = 0.0;
    for (int b = 0; b < 512; ++b) { s1 += part[b * 8 + g]; s2 += part[b * 8 + 4 + g]; }
    double cnt = 192.0 * 16384.0;
    double mean = s1 / cnt;
    double var = s2 / cnt - mean * mean;
    stats[g] = (float)mean;
    stats[4 + g] = (float)(1.0 / sqrt(var + 1e-5));
}

// ---------------- fused GN + ReLU + 1x1 conv + sigmoid at mask positions ----------------
__global__ void k_score(const float* __restrict__ hm, const float* __restrict__ stats,
                        const float* __restrict__ gamma, const float* __restrict__ beta,
                        const float* __restrict__ w2, const float* __restrict__ b2,
                        float* __restrict__ scores) {
    int q = blockIdx.x * 4 + (threadIdx.x >> 6);
    int lane = threadIdx.x & 63;
    if (q >= MASKM) return;
    const float* hp = hm + (size_t)q * KD;
    float s = 0.f;
    for (int c = lane; c < KD; c += 64) {
        int g = c / 192;
        float v = (hp[c] - stats[g]) * stats[4 + g] * gamma[c] + beta[c];
        s += fmaxf(v, 0.f) * w2[c];
    }
    for (int o = 32; o; o >>= 1) s += __shfl_down(s, o, 64);
    if (lane == 0) scores[q] = 1.f / (1.f + expf(-(s + b2[0])));
}

// ---------------- greedy NMS via 5-round iterative argmax (== stable sorted greedy) ----------------
__device__ __forceinline__ unsigned long long shfl_down_u64(unsigned long long v, int o) {
    unsigned lo = (unsigned)v, hi = (unsigned)(v >> 32);
    lo = __shfl_down(lo, o, 64);
    hi = __shfl_down(hi, o, 64);
    return ((unsigned long long)hi << 32) | lo;
}

__global__ void k_nms(const float* __restrict__ scores, const int* __restrict__ qi,
                      const int* __restrict__ qj, const int* __restrict__ durp,
                      float* __restrict__ out) {
    __shared__ unsigned long long key[MASKM];
    __shared__ float ss[MASKM], ee[MASKM];
    __shared__ unsigned char st[MASKM];     // 0 free, 1 suppressed, 2 kept, 3 picked-fallback
    __shared__ unsigned long long wm0[16], wm1[16];
    __shared__ int sh_keeper, keepq[5];
    __shared__ float sh_s0, sh_e0;
    int t = threadIdx.x;                    // 1024
    float delta = (float)(*durp) / 128.f;
    for (int i = t; i < MASKM; i += 1024) {
        unsigned sb = __float_as_uint(scores[i]);            // scores > 0: bits monotonic
        key[i] = ((unsigned long long)sb << 32) | (unsigned)(4095 - i);  // tie: lower q wins
        ss[i] = qi[i] * delta;
        ee[i] = (qj[i] + 1) * delta;
        st[i] = 0;
    }
    __syncthreads();
    for (int round = 0; round < 5; ++round) {
        unsigned long long b0 = 0, b1 = 0;
        for (int i = t; i < MASKM; i += 1024) {
            unsigned char s = st[i];
            unsigned long long k = key[i];
            if (s == 0) { if (k > b0) b0 = k; }
            else if (s == 1) { if (k > b1) b1 = k; }
        }
        for (int o = 32; o; o >>= 1) {
            unsigned long long u0 = shfl_down_u64(b0, o), u1 = shfl_down_u64(b1, o);
            if (u0 > b0) b0 = u0;
            if (u1 > b1) b1 = u1;
        }
        if ((t & 63) == 0) { wm0[t >> 6] = b0; wm1[t >> 6] = b1; }
        __syncthreads();
        if (t == 0) {
            unsigned long long B0 = 0, B1 = 0;
            for (int w = 0; w < 16; ++w) {
                if (wm0[w] > B0) B0 = wm0[w];
                if (wm1[w] > B1) B1 = wm1[w];
            }
            int keeper = (B0 != 0);
            unsigned long long B = keeper ? B0 : B1;
            int q = 4095 - (int)(B & 0xFFFFFFFFull);
            st[q] = keeper ? 2 : 3;
            sh_keeper = keeper;
            sh_s0 = ss[q]; sh_e0 = ee[q];
            keepq[round] = q;
        }
        __syncthreads();
        if (sh_keeper) {
            float s0 = sh_s0, e0 = sh_e0;
            for (int i = t; i < MASKM; i += 1024) {
                if (st[i] == 0) {
                    float inter = fminf(ee[i], e0) - fmaxf(ss[i], s0);
                    if (inter > 0.f) {
                        float uni = fmaxf(ee[i], e0) - fminf(ss[i], s0);
                        if (inter / uni > 0.5f) st[i] = 1;
                    }
                }
            }
        }
        __syncthreads();
    }
    if (t < 5) { out[t * 2] = ss[keepq[t]]; out[t * 2 + 1] = ee[keepq[t]]; }
}

// ---------------- launch ----------------
extern "C" void kernel_launch(void* const* d_in, const int* in_sizes, int n_in,
                              void* d_out, int out_size, void* d_ws, size_t ws_size,
                              hipStream_t stream) {
    const float* fea   = (const float*)d_in[0];
    const int*   dur   = (const int*)d_in[1];
    const float* w1    = (const float*)d_in[2];
    const float* gamma = (const float*)d_in[3];
    const float* beta  = (const float*)d_in[4];
    const float* w2    = (const float*)d_in[5];
    const float* b2    = (const float*)d_in[6];
    float* out = (float*)d_out;

    char* ws = (char*)d_ws;
    int*    qi     = (int*)(ws + OFF_QI);
    int*    qj     = (int*)(ws + OFF_QJ);
    int*    qidx   = (int*)(ws + OFF_QIDX);
    int*    apix   = (int*)(ws + OFF_APIX);
    int*    startv = (int*)(ws + OFF_START);
    double* part   = (double*)(ws + OFF_PART);
    float*  stats  = (float*)(ws + OFF_STAT);
    float*  scores = (float*)(ws + OFF_SC);
    float*  hm     = (float*)(ws + OFF_HM);
    unsigned short* AhU = (unsigned short*)(ws + OFF_AH);
    unsigned short* AlU = (unsigned short*)(ws + OFF_AL);
    unsigned short* BhU = (unsigned short*)(ws + OFF_BH);
    unsigned short* BlU = (unsigned short*)(ws + OFF_BL);
    float*  Yt     = (float*)(ws + OFF_YT);
    float*  X      = (float*)(ws + OFF_X);   // aliases Yt head

    // allow 144 KB dynamic LDS for k_gemm (one-time host-side attribute)
    static bool gemm_attr_set = false;
    if (!gemm_attr_set) {
        hipFuncSetAttribute((const void*)k_gemm,
                            hipFuncAttributeMaxDynamicSharedMemorySize, 3 * GB_SZ);
        gemm_attr_set = true;
    }

    k_rowstart<<<1, 128, 0, stream>>>(startv);
    k_fill<<<64, 256, 0, stream>>>(startv, qi, qj, qidx, apix);
    k_buildX<<<768, 64, 0, stream>>>(fea, qi, qj, X);
    k_prepA<<<dim3(12, 12), 256, 0, stream>>>(w1, AhU, AlU);
    k_trans<<<dim3(40, 12), 256, 0, stream>>>(X, NPAD, BhU, BlU);
    k_gemm<<<dim3(540), 512, 3 * GB_SZ, stream>>>(AhU, AlU, BhU, BlU, Yt);
    k_gather<<<512, 256, 0, stream>>>(Yt, qidx, apix, hm, part);
    k_finalize<<<1, 64, 0, stream>>>(part, stats);
    k_score<<<637, 256, 0, stream>>>(hm, stats, gamma, beta, w2, b2, scores);
    k_nms<<<1, 1024, 0, stream>>>(scores, qi, qj, dur, out);
}

// Round 2
// 308.473 us; speedup vs baseline: 1.0846x; 1.0846x over previous
//
#include <hip/hip_runtime.h>
#include <math.h>

// ---------------- problem constants ----------------
#define NPIX 128
#define MASKM 2548
#define NPAD 2560          // padded q count (20*128)
#define MG   6912          // GEMM M = 9 taps * 768
#define KD   768

typedef __attribute__((ext_vector_type(8))) short bf16x8;
typedef __attribute__((ext_vector_type(4))) float f32x4;
typedef __attribute__((ext_vector_type(16))) float f32x16;
typedef __attribute__((ext_vector_type(8))) unsigned short ushort8;

// ---------------- workspace layout ----------------
static constexpr size_t OFF_QI   = 0;
static constexpr size_t OFF_QJ   = OFF_QI + NPAD * 4;
static constexpr size_t OFF_QIDX = OFF_QJ + NPAD * 4;
static constexpr size_t OFF_APIX = OFF_QIDX + 16384 * 4;
static constexpr size_t OFF_START= OFF_APIX + 16384 * 4;
static constexpr size_t OFF_PART = OFF_START + 128 * 4;
static constexpr size_t OFF_STAT = OFF_PART + 512 * 8 * 8;
static constexpr size_t OFF_SC   = OFF_STAT + 256;
static constexpr size_t OFF_HM   = OFF_SC + NPAD * 4;
static constexpr size_t OFF_AH   = OFF_HM + (size_t)MASKM * KD * 4;
static constexpr size_t OFF_AL   = OFF_AH + (size_t)MG * KD * 2;
static constexpr size_t OFF_BH   = OFF_AL + (size_t)MG * KD * 2;
static constexpr size_t OFF_BL   = OFF_BH + (size_t)NPAD * KD * 2;
static constexpr size_t OFF_YT   = OFF_BL + (size_t)NPAD * KD * 2;
// X (7.9MB fp32) aliases the head of Yt (70.8MB): dead before k_gemm writes Yt.
static constexpr size_t OFF_X    = OFF_YT;

// ---------------- bf16 hi/lo split helpers ----------------
__device__ __forceinline__ unsigned short f2bf(float f) {
    unsigned u = __float_as_uint(f);
    u = u + 0x7FFFu + ((u >> 16) & 1u);       // RNE
    return (unsigned short)(u >> 16);
}
__device__ __forceinline__ float bf2f(unsigned short h) {
    return __uint_as_float(((unsigned)h) << 16);
}

// ---------------- mask structure (closed form) ----------------
__device__ __forceinline__ bool mask_allowed(int i, int d) {
    if (d == 0) return true;
    if (d <= 15) return true;
    if (d <= 31) return (d >= 17) && ((d & 1) == 1) && ((i & 1) == 0);
    if (d <= 63) return (d >= 35) && ((d & 3) == 3) && ((i & 3) == 0);
    return (d >= 71) && ((d & 7) == 7) && ((i & 7) == 0);
}
__device__ __forceinline__ bool masked_ij(int i, int j) {
    return (j >= i) && (j < NPIX) && (i >= 0) && mask_allowed(i, j - i);
}

// 1 block x 128: per-row q-offsets only (cheap)
__global__ void k_rowstart(int* startv) {
    __shared__ int cnt[NPIX];
    int i = threadIdx.x;
    int c = 0;
    for (int d = 0; i + d < NPIX; ++d) if (mask_allowed(i, d)) ++c;
    cnt[i] = c;
    __syncthreads();
    if (i == 0) {
        int s = 0;
        for (int r = 0; r < NPIX; ++r) { startv[r] = s; s += cnt[r]; }
    }
}

// 64 blocks x 256: one thread per pixel -> qidx, apix, qi/qj
__global__ void k_fill(const int* __restrict__ startv, int* __restrict__ qi,
                       int* __restrict__ qj, int* __restrict__ qidx,
                       int* __restrict__ apix) {
    int p = blockIdx.x * 256 + threadIdx.x;
    int i = p >> 7, j = p & 127;
    int q = -1;
    if (masked_ij(i, j)) {
        int d = j - i, r = 0;
        for (int dd = 0; dd < d; ++dd) r += mask_allowed(i, dd) ? 1 : 0;
        q = startv[i] + r;
        qi[q] = i; qj[q] = j;
    }
    qidx[p] = q;
    int act = 0;
    #pragma unroll
    for (int dy = -1; dy <= 1; ++dy)
        #pragma unroll
        for (int dx = -1; dx <= 1; ++dx)
            if (masked_ij(i + dy, j + dx)) act = 1;
    apix[p] = act;
}

// ---------------- X[c][q] = max(fea[c, i..j]) via sparse table ----------------
__global__ void k_buildX(const float* __restrict__ fea, const int* __restrict__ qi,
                         const int* __restrict__ qj, float* __restrict__ X) {
    __shared__ float tab[8][NPIX];
    int c = blockIdx.x, t = threadIdx.x;
    tab[0][t]      = fea[c * NPIX + t];
    tab[0][t + 64] = fea[c * NPIX + t + 64];
    __syncthreads();
    for (int l = 1; l < 8; ++l) {
        int half = 1 << (l - 1), full = 1 << l;
        for (int i = t; i < NPIX; i += 64)
            if (i + full <= NPIX) tab[l][i] = fmaxf(tab[l - 1][i], tab[l - 1][i + half]);
        __syncthreads();
    }
    for (int q = t; q < NPAD; q += 64) {
        float v = 0.f;
        if (q < MASKM) {
            int i = qi[q], j = qj[q];
            int len = j - i + 1;
            int l = 31 - __clz(len);
            v = fmaxf(tab[l][i], tab[l][j + 1 - (1 << l)]);
        }
        X[c * NPAD + q] = v;
    }
}

// ---------------- fused reorder+split: w1[co][ci*9+tap] -> Ah/Al[(tap*768+co)][ci] ----------------
__global__ __launch_bounds__(256) void k_prepA(const float* __restrict__ w1,
                                               unsigned short* __restrict__ Ah,
                                               unsigned short* __restrict__ Al) {
    __shared__ float tile[64 * 144];   // [co 64][ci16*9tap = 144]
    int co0 = blockIdx.x * 64, ci0 = blockIdx.y * 64;
    int tid = threadIdx.x;
    for (int s = 0; s < 4; ++s) {
        int cib = ci0 + s * 16;
        __syncthreads();
        for (int idx = tid; idx < 2304; idx += 256) {
            int row = idx / 36, c4 = idx % 36;
            float4 v = *(const float4*)(w1 + (size_t)(co0 + row) * MG + cib * 9 + c4 * 4);
            *(float4*)&tile[row * 144 + c4 * 4] = v;
        }
        __syncthreads();
        for (int idx = tid; idx < 1152; idx += 256) {
            int tap = idx / 128;
            int rem = idx - tap * 128;
            int co = rem >> 1, half = rem & 1;
            ushort8 vh, vl;
            #pragma unroll
            for (int c = 0; c < 8; ++c) {
                float v = tile[co * 144 + (half * 8 + c) * 9 + tap];
                unsigned short hi = f2bf(v);
                vh[c] = hi;
                vl[c] = f2bf(v - bf2f(hi));
            }
            size_t ob = (size_t)(tap * 768 + co0 + co) * KD + cib + half * 8;
            *(ushort8*)(Ah + ob) = vh;
            *(ushort8*)(Al + ob) = vl;
        }
    }
}

// ---------------- transpose + bf16 hi/lo split: src[768][C] -> dst[C][768] ----------------
__global__ void k_trans(const float* __restrict__ src, int C,
                        unsigned short* __restrict__ dh, unsigned short* __restrict__ dl) {
    __shared__ float tile[64][65];
    int c0 = blockIdx.x * 64, k0 = blockIdx.y * 64;
    int t = threadIdx.x;
    int r = t >> 2, cq = (t & 3) << 4;
    const float* s = src + (size_t)(k0 + r) * C + c0 + cq;
    #pragma unroll
    for (int u = 0; u < 16; u += 4) {
        float4 v = *(const float4*)(s + u);
        tile[r][cq + u]     = v.x;
        tile[r][cq + u + 1] = v.y;
        tile[r][cq + u + 2] = v.z;
        tile[r][cq + u + 3] = v.w;
    }
    __syncthreads();
    size_t ob = (size_t)(c0 + r) * KD + k0 + cq;
    #pragma unroll
    for (int u = 0; u < 16; ++u) {
        float v = tile[cq + u][r];
        unsigned short hi = f2bf(v);
        float lo = v - bf2f(hi);
        dh[ob + u] = hi;
        dl[ob + u] = f2bf(lo);
    }
}

// ---------------- bf16x3 MFMA GEMM: Yt[n][m] = sum_k A[m][k] * B[n][k] ----------------
// 32x32x16 MFMA (2495 TF ceiling vs 2075 for 16x16), BM=256 BN=320 BK=32,
// grid = 27x8 = 216 blocks -> ONE dispatch round (fixes R1's 70% packing),
// 216 = 8 XCDs x 27: each XCD owns one 320-wide B panel (983 KB, L2-resident).
// 2-deep LDS double buffer (2 x 72 KB); loads issued at tile start, single
// vmcnt(0) at tile end (compute/tile ~3900 cyc >> HBM latency -> free drain).
// Chunk-XOR LDS swizzle identical to prior kernel (measured 0 conflicts).
#define BUFSZ   73728      // Ah(16K) | Al(16K) | Bh(20K) | Bl(20K)
#define SB_AL   16384
#define SB_BH   32768
#define SB_BL   53248

__global__ __launch_bounds__(512, 2) void k_gemm(const unsigned short* __restrict__ Ah,
                                                 const unsigned short* __restrict__ Al,
                                                 const unsigned short* __restrict__ Bh,
                                                 const unsigned short* __restrict__ Bl,
                                                 float* __restrict__ Yt) {
    extern __shared__ char sm[];               // 2 * BUFSZ = 144 KB dynamic LDS
    int tid = threadIdx.x;
    int wave = tid >> 6, lane = tid & 63;

    // 216 blocks = 8 xcd x 27: each XCD gets one N-panel, streams all M-tiles.
    int bid = (int)blockIdx.x;
    int xcd = bid & 7, loc = bid >> 3;         // loc in 0..26
    int m0 = loc * 256, n0 = xcd * 320;

    int wm = (wave & 3) << 6, wn = (wave >> 2) * 160;  // 4M x 2N wave grid, 64x160/wave
    int r4 = lane >> 2, c4 = lane & 3;
    int r32 = lane & 31, hi2 = lane >> 5;
    int csw = c4 ^ ((r4 >> 1) & 3);                    // staging chunk swizzle
    int rsw = (r32 >> 1) & 3;                          // read-side row swizzle bits
    // ks=0 fragment byte offsets (XOR with 32 flips to ks=1 chunk)
    int abase = (wm + r32) * 64 + ((hi2 ^ rsw) << 4);
    int bbase = (wn + r32) * 64 + ((hi2 ^ rsw) << 4);

    // 9 stage slots per wave: gid = wave*9+s over 72 total.
    // gid 0-15: Ah 16-row groups; 16-31: Al; 32-51: Bh; 52-71: Bl.
    const unsigned short* sp[9];
    int so[9];
    #pragma unroll
    for (int s = 0; s < 9; ++s) {
        int gid = wave * 9 + s;
        const unsigned short* base;
        int row0, ldso;
        if (gid < 16)      { base = Ah; row0 = m0 + gid * 16;        ldso = gid * 1024; }
        else if (gid < 32) { base = Al; row0 = m0 + (gid - 16) * 16; ldso = SB_AL + (gid - 16) * 1024; }
        else if (gid < 52) { base = Bh; row0 = n0 + (gid - 32) * 16; ldso = SB_BH + (gid - 32) * 1024; }
        else               { base = Bl; row0 = n0 + (gid - 52) * 16; ldso = SB_BL + (gid - 52) * 1024; }
        sp[s] = base + (size_t)(row0 + r4) * KD + csw * 8;
        so[s] = ldso;
    }

    f32x16 acc[2][5] = {};                     // 2 m-frags x 5 n-frags of 32x32

    char* CB = sm;                             // compute buffer
    char* NB = sm + BUFSZ;                     // staging buffer (next tile)

    #define STAGE(s, koff) __builtin_amdgcn_global_load_lds( \
        (const __attribute__((address_space(1))) unsigned int*)(sp[s] + (koff)), \
        (__attribute__((address_space(3))) unsigned int*)(NB + so[s]), 16, 0, 0)
    #define ARD(hl, mf, ks) (*(const bf16x8*)(CB + (hl) * 16384 + ((abase ^ ((ks) << 5)) + (mf) * 2048)))
    #define BRD(hl, nf, ks) (*(const bf16x8*)(CB + SB_BH + (hl) * 20480 + ((bbase ^ ((ks) << 5)) + (nf) * 2048)))
    #define TRIP(mf, nf, xh, xl, yh, yl) \
        acc[mf][nf] = __builtin_amdgcn_mfma_f32_32x32x16_bf16(xh, yh, acc[mf][nf], 0, 0, 0); \
        acc[mf][nf] = __builtin_amdgcn_mfma_f32_32x32x16_bf16(xh, yl, acc[mf][nf], 0, 0, 0); \
        acc[mf][nf] = __builtin_amdgcn_mfma_f32_32x32x16_bf16(xl, yh, acc[mf][nf], 0, 0, 0);

    // prologue: stage tile 0 into CB, drain, sync.
    {
        char* tmp = CB; CB = NB; NB = tmp;     // make STAGE target = first buffer
        #pragma unroll
        for (int s = 0; s < 9; ++s) STAGE(s, 0);
        char* t2 = CB; CB = NB; NB = t2;       // restore roles
    }
    asm volatile("s_waitcnt vmcnt(0)" ::: "memory");
    __builtin_amdgcn_s_barrier();

    for (int t = 0; t < 24; ++t) {             // K = 768 = 24 tiles of 32
        int kn = (t + 1) * 32;
        bool stg = (t < 23);
        bf16x8 a0h, a0l, a1h, a1l;
        bf16x8 b0h, b0l, b1h, b1l, b2h, b2l, b3h, b3l, b4h, b4l;

        // ================= phase ks=0 =================
        a0h = ARD(0, 0, 0); a0l = ARD(1, 0, 0);
        a1h = ARD(0, 1, 0); a1l = ARD(1, 1, 0);
        b0h = BRD(0, 0, 0); b0l = BRD(1, 0, 0);
        b1h = BRD(0, 1, 0); b1l = BRD(1, 1, 0);
        b2h = BRD(0, 2, 0); b2l = BRD(1, 2, 0);
        if (stg) { STAGE(0, kn); STAGE(1, kn); STAGE(2, kn); STAGE(3, kn); STAGE(4, kn); }
        asm volatile("" ::: "memory");
        __builtin_amdgcn_s_barrier();
        __builtin_amdgcn_s_setprio(1);
        TRIP(0, 0, a0h, a0l, b0h, b0l)
        TRIP(0, 1, a0h, a0l, b1h, b1l)
        TRIP(0, 2, a0h, a0l, b2h, b2l)
        TRIP(1, 0, a1h, a1l, b0h, b0l)
        TRIP(1, 1, a1h, a1l, b1h, b1l)
        TRIP(1, 2, a1h, a1l, b2h, b2l)
        __builtin_amdgcn_s_setprio(0);
        __builtin_amdgcn_sched_barrier(0);     // keep b3/b4 reads after the cluster (VGPR cap)
        b3h = BRD(0, 3, 0); b3l = BRD(1, 3, 0);
        b4h = BRD(0, 4, 0); b4l = BRD(1, 4, 0);
        __builtin_amdgcn_s_setprio(1);
        TRIP(0, 3, a0h, a0l, b3h, b3l)
        TRIP(0, 4, a0h, a0l, b4h, b4l)
        TRIP(1, 3, a1h, a1l, b3h, b3l)
        TRIP(1, 4, a1h, a1l, b4h, b4l)
        __builtin_amdgcn_s_setprio(0);
        asm volatile("" ::: "memory");
        __builtin_amdgcn_s_barrier();

        // ================= phase ks=1 =================
        a0h = ARD(0, 0, 1); a0l = ARD(1, 0, 1);
        a1h = ARD(0, 1, 1); a1l = ARD(1, 1, 1);
        b0h = BRD(0, 0, 1); b0l = BRD(1, 0, 1);
        b1h = BRD(0, 1, 1); b1l = BRD(1, 1, 1);
        b2h = BRD(0, 2, 1); b2l = BRD(1, 2, 1);
        if (stg) { STAGE(5, kn); STAGE(6, kn); STAGE(7, kn); STAGE(8, kn); }
        asm volatile("" ::: "memory");
        __builtin_amdgcn_s_barrier();
        __builtin_amdgcn_s_setprio(1);
        TRIP(0, 0, a0h, a0l, b0h, b0l)
        TRIP(0, 1, a0h, a0l, b1h, b1l)
        TRIP(0, 2, a0h, a0l, b2h, b2l)
        TRIP(1, 0, a1h, a1l, b0h, b0l)
        TRIP(1, 1, a1h, a1l, b1h, b1l)
        TRIP(1, 2, a1h, a1l, b2h, b2l)
        __builtin_amdgcn_s_setprio(0);
        __builtin_amdgcn_sched_barrier(0);
        b3h = BRD(0, 3, 1); b3l = BRD(1, 3, 1);
        b4h = BRD(0, 4, 1); b4l = BRD(1, 4, 1);
        __builtin_amdgcn_s_setprio(1);
        TRIP(0, 3, a0h, a0l, b3h, b3l)
        TRIP(0, 4, a0h, a0l, b4h, b4l)
        TRIP(1, 3, a1h, a1l, b3h, b3l)
        TRIP(1, 4, a1h, a1l, b4h, b4l)
        __builtin_amdgcn_s_setprio(0);
        // next-tile buffer must be fully resident before anyone reads it;
        // the 9 loads were issued ~3900 cyc ago -> near-free drain.
        if (stg) asm volatile("s_waitcnt vmcnt(0)" ::: "memory");
        asm volatile("" ::: "memory");
        __builtin_amdgcn_s_barrier();

        char* tmp = CB; CB = NB; NB = tmp;     // swap double buffers
    }

    // epilogue: C/D layout of 32x32: col(n)=lane&31, row(m)=(reg&3)+8*(reg>>2)+4*(lane>>5)
    #pragma unroll
    for (int mf = 0; mf < 2; ++mf)
        #pragma unroll
        for (int nf = 0; nf < 5; ++nf) {
            int n = n0 + wn + nf * 32 + r32;
            size_t rowb = (size_t)n * MG + m0 + wm + mf * 32 + 4 * hi2;
            #pragma unroll
            for (int g = 0; g < 4; ++g) {
                f32x4 v = { acc[mf][nf][g * 4 + 0], acc[mf][nf][g * 4 + 1],
                            acc[mf][nf][g * 4 + 2], acc[mf][nf][g * 4 + 3] };
                *(f32x4*)(Yt + rowb + 8 * g) = v;
            }
        }
    #undef STAGE
    #undef ARD
    #undef BRD
    #undef TRIP
}

// ---------------- gather taps -> hm (masked rows) + GN partial sums (active pixels only) ----------------
__global__ __launch_bounds__(256) void k_gather(const float* __restrict__ Yt,
                                                const int* __restrict__ qidx,
                                                const int* __restrict__ apix,
                                                float* __restrict__ hm,
                                                double* __restrict__ part) {
    __shared__ double red1[256 * 4], red2[256 * 4];
    int tid = threadIdx.x;
    int wave = tid >> 6, lane = tid & 63;
    double a1[3] = {0, 0, 0}, a2[3] = {0, 0, 0};
    int gs[3];
    #pragma unroll
    for (int s = 0; s < 3; ++s) gs[s] = (64 * s + lane) / 48;

    for (int it = 0; it < 8; ++it) {
        int p = blockIdx.x * 32 + wave * 8 + it;   // wave-uniform pixel
        if (!apix[p]) continue;
        int y = p >> 7, x = p & 127;
        float4 hv[3] = {};
        #pragma unroll
        for (int tap = 0; tap < 9; ++tap) {
            int i = y + tap / 3 - 1, j = x + tap % 3 - 1;
            if ((unsigned)i < 128u && (unsigned)j < 128u) {
                int q = qidx[i * NPIX + j];
                if (q >= 0) {
                    const float* yr = Yt + (size_t)q * MG + tap * 768 + lane * 4;
                    #pragma unroll
                    for (int s = 0; s < 3; ++s) {
                        float4 v = *(const float4*)(yr + s * 256);
                        hv[s].x += v.x; hv[s].y += v.y; hv[s].z += v.z; hv[s].w += v.w;
                    }
                }
            }
        }
        int qp = qidx[p];
        if (qp >= 0) {
            #pragma unroll
            for (int s = 0; s < 3; ++s)
                *(float4*)(hm + (size_t)qp * KD + s * 256 + lane * 4) = hv[s];
        }
        #pragma unroll
        for (int s = 0; s < 3; ++s) {
            a1[s] += (double)hv[s].x + (double)hv[s].y + (double)hv[s].z + (double)hv[s].w;
            a2[s] += (double)hv[s].x * hv[s].x + (double)hv[s].y * hv[s].y +
                     (double)hv[s].z * hv[s].z + (double)hv[s].w * hv[s].w;
        }
    }
    #pragma unroll
    for (int g = 0; g < 4; ++g) { red1[tid * 4 + g] = 0.0; red2[tid * 4 + g] = 0.0; }
    #pragma unroll
    for (int s = 0; s < 3; ++s) { red1[tid * 4 + gs[s]] = a1[s]; red2[tid * 4 + gs[s]] = a2[s]; }
    __syncthreads();
    if (tid < 4) {
        double s1 = 0.0, s2 = 0.0;
        for (int i = 0; i < 256; ++i) { s1 += red1[i * 4 + tid]; s2 += red2[i * 4 + tid]; }
        part[blockIdx.x * 8 + tid] = s1;
        part[blockIdx.x * 8 + 4 + tid] = s2;
    }
}

__global__ void k_finalize(const double* __restrict__ part, float* __restrict__ stats) {
    int g = threadIdx.x;
    if (g >= 4) return;
    double s1 = 0.0, s2 = 0.0;
    for (int b = 0; b < 512; ++b) { s1 += part[b * 8 + g]; s2 += part[b * 8 + 4 + g]; }
    double cnt = 192.0 * 16384.0;
    double mean = s1 / cnt;
    double var = s2 / cnt - mean * mean;
    stats[g] = (float)mean;
    stats[4 + g] = (float)(1.0 / sqrt(var + 1e-5));
}

// ---------------- fused GN + ReLU + 1x1 conv + sigmoid at mask positions ----------------
__global__ void k_score(const float* __restrict__ hm, const float* __restrict__ stats,
                        const float* __restrict__ gamma, const float* __restrict__ beta,
                        const float* __restrict__ w2, const float* __restrict__ b2,
                        float* __restrict__ scores) {
    int q = blockIdx.x * 4 + (threadIdx.x >> 6);
    int lane = threadIdx.x & 63;
    if (q >= MASKM) return;
    const float* hp = hm + (size_t)q * KD;
    float s = 0.f;
    for (int c = lane; c < KD; c += 64) {
        int g = c / 192;
        float v = (hp[c] - stats[g]) * stats[4 + g] * gamma[c] + beta[c];
        s += fmaxf(v, 0.f) * w2[c];
    }
    for (int o = 32; o; o >>= 1) s += __shfl_down(s, o, 64);
    if (lane == 0) scores[q] = 1.f / (1.f + expf(-(s + b2[0])));
}

// ---------------- greedy NMS via 5-round iterative argmax (== stable sorted greedy) ----------------
__device__ __forceinline__ unsigned long long shfl_down_u64(unsigned long long v, int o) {
    unsigned lo = (unsigned)v, hi = (unsigned)(v >> 32);
    lo = __shfl_down(lo, o, 64);
    hi = __shfl_down(hi, o, 64);
    return ((unsigned long long)hi << 32) | lo;
}

__global__ void k_nms(const float* __restrict__ scores, const int* __restrict__ qi,
                      const int* __restrict__ qj, const int* __restrict__ durp,
                      float* __restrict__ out) {
    __shared__ unsigned long long key[MASKM];
    __shared__ float ss[MASKM], ee[MASKM];
    __shared__ unsigned char st[MASKM];     // 0 free, 1 suppressed, 2 kept, 3 picked-fallback
    __shared__ unsigned long long wm0[16], wm1[16];
    __shared__ int sh_keeper, keepq[5];
    __shared__ float sh_s0, sh_e0;
    int t = threadIdx.x;                    // 1024
    float delta = (float)(*durp) / 128.f;
    for (int i = t; i < MASKM; i += 1024) {
        unsigned sb = __float_as_uint(scores[i]);            // scores > 0: bits monotonic
        key[i] = ((unsigned long long)sb << 32) | (unsigned)(4095 - i);  // tie: lower q wins
        ss[i] = qi[i] * delta;
        ee[i] = (qj[i] + 1) * delta;
        st[i] = 0;
    }
    __syncthreads();
    for (int round = 0; round < 5; ++round) {
        unsigned long long b0 = 0, b1 = 0;
        for (int i = t; i < MASKM; i += 1024) {
            unsigned char s = st[i];
            unsigned long long k = key[i];
            if (s == 0) { if (k > b0) b0 = k; }
            else if (s == 1) { if (k > b1) b1 = k; }
        }
        for (int o = 32; o; o >>= 1) {
            unsigned long long u0 = shfl_down_u64(b0, o), u1 = shfl_down_u64(b1, o);
            if (u0 > b0) b0 = u0;
            if (u1 > b1) b1 = u1;
        }
        if ((t & 63) == 0) { wm0[t >> 6] = b0; wm1[t >> 6] = b1; }
        __syncthreads();
        if (t == 0) {
            unsigned long long B0 = 0, B1 = 0;
            for (int w = 0; w < 16; ++w) {
                if (wm0[w] > B0) B0 = wm0[w];
                if (wm1[w] > B1) B1 = wm1[w];
            }
            int keeper = (B0 != 0);
            unsigned long long B = keeper ? B0 : B1;
            int q = 4095 - (int)(B & 0xFFFFFFFFull);
            st[q] = keeper ? 2 : 3;
            sh_keeper = keeper;
            sh_s0 = ss[q]; sh_e0 = ee[q];
            keepq[round] = q;
        }
        __syncthreads();
        if (sh_keeper) {
            float s0 = sh_s0, e0 = sh_e0;
            for (int i = t; i < MASKM; i += 1024) {
                if (st[i] == 0) {
                    float inter = fminf(ee[i], e0) - fmaxf(ss[i], s0);
                    if (inter > 0.f) {
                        float uni = fmaxf(ee[i], e0) - fminf(ss[i], s0);
                        if (inter / uni > 0.5f) st[i] = 1;
                    }
                }
            }
        }
        __syncthreads();
    }
    if (t < 5) { out[t * 2] = ss[keepq[t]]; out[t * 2 + 1] = ee[keepq[t]]; }
}

// ---------------- launch ----------------
extern "C" void kernel_launch(void* const* d_in, const int* in_sizes, int n_in,
                              void* d_out, int out_size, void* d_ws, size_t ws_size,
                              hipStream_t stream) {
    const float* fea   = (const float*)d_in[0];
    const int*   dur   = (const int*)d_in[1];
    const float* w1    = (const float*)d_in[2];
    const float* gamma = (const float*)d_in[3];
    const float* beta  = (const float*)d_in[4];
    const float* w2    = (const float*)d_in[5];
    const float* b2    = (const float*)d_in[6];
    float* out = (float*)d_out;

    char* ws = (char*)d_ws;
    int*    qi     = (int*)(ws + OFF_QI);
    int*    qj     = (int*)(ws + OFF_QJ);
    int*    qidx   = (int*)(ws + OFF_QIDX);
    int*    apix   = (int*)(ws + OFF_APIX);
    int*    startv = (int*)(ws + OFF_START);
    double* part   = (double*)(ws + OFF_PART);
    float*  stats  = (float*)(ws + OFF_STAT);
    float*  scores = (float*)(ws + OFF_SC);
    float*  hm     = (float*)(ws + OFF_HM);
    unsigned short* AhU = (unsigned short*)(ws + OFF_AH);
    unsigned short* AlU = (unsigned short*)(ws + OFF_AL);
    unsigned short* BhU = (unsigned short*)(ws + OFF_BH);
    unsigned short* BlU = (unsigned short*)(ws + OFF_BL);
    float*  Yt     = (float*)(ws + OFF_YT);
    float*  X      = (float*)(ws + OFF_X);   // aliases Yt head

    // allow 144 KB dynamic LDS for k_gemm (one-time host-side attribute)
    static bool gemm_attr_set = false;
    if (!gemm_attr_set) {
        hipFuncSetAttribute((const void*)k_gemm,
                            hipFuncAttributeMaxDynamicSharedMemorySize, 2 * BUFSZ);
        gemm_attr_set = true;
    }

    k_rowstart<<<1, 128, 0, stream>>>(startv);
    k_fill<<<64, 256, 0, stream>>>(startv, qi, qj, qidx, apix);
    k_buildX<<<768, 64, 0, stream>>>(fea, qi, qj, X);
    k_prepA<<<dim3(12, 12), 256, 0, stream>>>(w1, AhU, AlU);
    k_trans<<<dim3(40, 12), 256, 0, stream>>>(X, NPAD, BhU, BlU);
    k_gemm<<<dim3(216), 512, 2 * BUFSZ, stream>>>(AhU, AlU, BhU, BlU, Yt);
    k_gather<<<512, 256, 0, stream>>>(Yt, qidx, apix, hm, part);
    k_finalize<<<1, 64, 0, stream>>>(part, stats);
    k_score<<<637, 256, 0, stream>>>(hm, stats, gamma, beta, w2, b2, scores);
    k_nms<<<1, 1024, 0, stream>>>(scores, qi, qj, dur, out);
}

// Round 4
// 283.922 us; speedup vs baseline: 1.1783x; 1.0865x over previous
//
#include <hip/hip_runtime.h>
#include <math.h>

// ---------------- problem constants ----------------
#define NPIX 128
#define MASKM 2548
#define NPAD 2560          // padded q count (20*128)
#define MG   6912          // GEMM M = 9 taps * 768
#define KD   768

typedef __attribute__((ext_vector_type(8))) short bf16x8;
typedef __attribute__((ext_vector_type(4))) float f32x4;
typedef __attribute__((ext_vector_type(16))) float f32x16;
typedef __attribute__((ext_vector_type(8))) unsigned short ushort8;

// ---------------- workspace layout ----------------
static constexpr size_t OFF_QI   = 0;
static constexpr size_t OFF_QJ   = OFF_QI + NPAD * 4;
static constexpr size_t OFF_QIDX = OFF_QJ + NPAD * 4;
static constexpr size_t OFF_APIX = OFF_QIDX + 16384 * 4;
static constexpr size_t OFF_START= OFF_APIX + 16384 * 4;
static constexpr size_t OFF_PART = OFF_START + 128 * 4;
static constexpr size_t OFF_STAT = OFF_PART + 512 * 8 * 8;
static constexpr size_t OFF_SC   = OFF_STAT + 256;
static constexpr size_t OFF_HM   = OFF_SC + NPAD * 4;
static constexpr size_t OFF_AH   = OFF_HM + (size_t)MASKM * KD * 4;
static constexpr size_t OFF_AL   = OFF_AH + (size_t)MG * KD * 2;
static constexpr size_t OFF_BH   = OFF_AL + (size_t)MG * KD * 2;
static constexpr size_t OFF_BL   = OFF_BH + (size_t)NPAD * KD * 2;
static constexpr size_t OFF_YT   = OFF_BL + (size_t)NPAD * KD * 2;
// X (7.9MB fp32) aliases the head of Yt (70.8MB): dead before k_gemm writes Yt.
static constexpr size_t OFF_X    = OFF_YT;

// ---------------- bf16 hi/lo split helpers ----------------
__device__ __forceinline__ unsigned short f2bf(float f) {
    unsigned u = __float_as_uint(f);
    u = u + 0x7FFFu + ((u >> 16) & 1u);       // RNE
    return (unsigned short)(u >> 16);
}
__device__ __forceinline__ float bf2f(unsigned short h) {
    return __uint_as_float(((unsigned)h) << 16);
}

// ---------------- mask structure (closed form) ----------------
__device__ __forceinline__ bool mask_allowed(int i, int d) {
    if (d == 0) return true;
    if (d <= 15) return true;
    if (d <= 31) return (d >= 17) && ((d & 1) == 1) && ((i & 1) == 0);
    if (d <= 63) return (d >= 35) && ((d & 3) == 3) && ((i & 3) == 0);
    return (d >= 71) && ((d & 7) == 7) && ((i & 7) == 0);
}
__device__ __forceinline__ bool masked_ij(int i, int j) {
    return (j >= i) && (j < NPIX) && (i >= 0) && mask_allowed(i, j - i);
}

// 64 blocks x 256: one thread per pixel -> qidx, apix, qi/qj.
// Row-start offsets recomputed per block in LDS (absorbs old k_rowstart).
// Block 0 also zeroes the 8 GN accumulator doubles (read by k_score).
__global__ void k_fill(int* __restrict__ qi, int* __restrict__ qj,
                       int* __restrict__ qidx, int* __restrict__ apix,
                       double* __restrict__ part) {
    __shared__ int cnt[NPIX];
    __shared__ int startv[NPIX];
    int tid = threadIdx.x;
    if (tid < NPIX) {
        int c = 0;
        for (int d = 0; tid + d < NPIX; ++d) if (mask_allowed(tid, d)) ++c;
        cnt[tid] = c;
    }
    __syncthreads();
    if (tid == 0) {
        int s = 0;
        for (int r = 0; r < NPIX; ++r) { startv[r] = s; s += cnt[r]; }
    }
    __syncthreads();
    int p = blockIdx.x * 256 + tid;
    int i = p >> 7, j = p & 127;
    int q = -1;
    if (masked_ij(i, j)) {
        int d = j - i, r = 0;
        for (int dd = 0; dd < d; ++dd) r += mask_allowed(i, dd) ? 1 : 0;
        q = startv[i] + r;
        qi[q] = i; qj[q] = j;
    }
    qidx[p] = q;
    int act = 0;
    #pragma unroll
    for (int dy = -1; dy <= 1; ++dy)
        #pragma unroll
        for (int dx = -1; dx <= 1; ++dx)
            if (masked_ij(i + dy, j + dx)) act = 1;
    apix[p] = act;
    if (blockIdx.x == 0 && tid < 8) part[tid] = 0.0;
}

// ---------------- X[c][q] = max(fea[c, i..j]) via sparse table ----------------
__global__ void k_buildX(const float* __restrict__ fea, const int* __restrict__ qi,
                         const int* __restrict__ qj, float* __restrict__ X) {
    __shared__ float tab[8][NPIX];
    int c = blockIdx.x, t = threadIdx.x;    // 128 threads
    tab[0][t] = fea[c * NPIX + t];
    __syncthreads();
    #pragma unroll
    for (int l = 1; l < 8; ++l) {
        int half = 1 << (l - 1), full = 1 << l;
        if (t + full <= NPIX) tab[l][t] = fmaxf(tab[l - 1][t], tab[l - 1][t + half]);
        __syncthreads();
    }
    #pragma unroll
    for (int it = 0; it < 20; ++it) {
        int q = it * 128 + t;
        float v = 0.f;
        if (q < MASKM) {
            int i = qi[q], j = qj[q];
            int len = j - i + 1;
            int l = 31 - __clz(len);
            v = fmaxf(tab[l][i], tab[l][j + 1 - (1 << l)]);
        }
        X[c * NPAD + q] = v;
    }
}

// ---------------- fused reorder+split: w1[co][ci*9+tap] -> Ah/Al[(tap*768+co)][ci] ----------------
#define PASTR 148   // padded float stride (148*4 B: 16B-aligned, non-pow2 banks)
__global__ __launch_bounds__(256) void k_prepA(const float* __restrict__ w1,
                                               unsigned short* __restrict__ Ah,
                                               unsigned short* __restrict__ Al) {
    __shared__ float tile[64 * PASTR];   // [co 64][ci16*9tap = 144 used]
    int co0 = blockIdx.x * 64, ci0 = blockIdx.y * 64;
    int tid = threadIdx.x;
    for (int s = 0; s < 4; ++s) {
        int cib = ci0 + s * 16;
        __syncthreads();
        for (int idx = tid; idx < 2304; idx += 256) {
            int row = idx / 36, c4 = idx % 36;
            float4 v = *(const float4*)(w1 + (size_t)(co0 + row) * MG + cib * 9 + c4 * 4);
            *(float4*)&tile[row * PASTR + c4 * 4] = v;
        }
        __syncthreads();
        for (int idx = tid; idx < 1152; idx += 256) {
            int tap = idx / 128;
            int rem = idx - tap * 128;
            int co = rem >> 1, half = rem & 1;
            ushort8 vh, vl;
            #pragma unroll
            for (int c = 0; c < 8; ++c) {
                float v = tile[co * PASTR + (half * 8 + c) * 9 + tap];
                unsigned short hi = f2bf(v);
                vh[c] = hi;
                vl[c] = f2bf(v - bf2f(hi));
            }
            size_t ob = (size_t)(tap * 768 + co0 + co) * KD + cib + half * 8;
            *(ushort8*)(Ah + ob) = vh;
            *(ushort8*)(Al + ob) = vl;
        }
    }
}

// ---------------- transpose + bf16 hi/lo split: src[768][C] -> dst[C][768] ----------------
__global__ void k_trans(const float* __restrict__ src, int C,
                        unsigned short* __restrict__ dh, unsigned short* __restrict__ dl) {
    __shared__ float tile[64][65];
    int c0 = blockIdx.x * 64, k0 = blockIdx.y * 64;
    int t = threadIdx.x;
    int r = t >> 2, cq = (t & 3) << 4;
    const float* s = src + (size_t)(k0 + r) * C + c0 + cq;
    #pragma unroll
    for (int u = 0; u < 16; u += 4) {
        float4 v = *(const float4*)(s + u);
        tile[r][cq + u]     = v.x;
        tile[r][cq + u + 1] = v.y;
        tile[r][cq + u + 2] = v.z;
        tile[r][cq + u + 3] = v.w;
    }
    __syncthreads();
    size_t ob = (size_t)(c0 + r) * KD + k0 + cq;
    #pragma unroll
    for (int u = 0; u < 16; ++u) {
        float v = tile[cq + u][r];
        unsigned short hi = f2bf(v);
        float lo = v - bf2f(hi);
        dh[ob + u] = hi;
        dl[ob + u] = f2bf(lo);
    }
}

// ---------------- bf16x3 MFMA GEMM: Yt[n][m] = sum_k A[m][k] * B[n][k] ----------------
// 32x32x16 MFMA, BM=256 BN=320 BK=32, grid = 216 = 8 XCD x 27 (one round).
// CHUNK-MAJOR LDS slots: each 16-row slot = [kchunk 0..3][row 0..15] x 16B, so the
// 32x32 fragment read (lane l -> row l&31, chunk 2ks+(l>>5)) is 8 lanes per 128
// contiguous bytes -> every bank exactly once -> zero conflicts by construction
// (R2's row-major slots measured exactly +4 cyc/ds_read_b128 = 4.6M conflicts).
// One real barrier per tile (intra-tile: waves only READ shared buffer, no hazard);
// sched_barrier(0)-separated clusters keep <=16 live B-regs and let anti-phased
// waves overlap LDS reads with MFMA. __syncthreads at tile end doubles as the
// vmcnt(0) drain of the 9 next-tile staging loads (issued ~5 clusters earlier).
#define BUFSZ   73728      // Ah(16K) | Al(16K) | Bh(20K) | Bl(20K)
#define SB_BH   32768

__global__ __launch_bounds__(512, 2) void k_gemm(const unsigned short* __restrict__ Ah,
                                                 const unsigned short* __restrict__ Al,
                                                 const unsigned short* __restrict__ Bh,
                                                 const unsigned short* __restrict__ Bl,
                                                 float* __restrict__ Yt) {
    extern __shared__ char sm[];               // 2 * BUFSZ = 144 KB dynamic LDS
    int tid = threadIdx.x;
    int wave = tid >> 6, lane = tid & 63;

    int bid = (int)blockIdx.x;
    int xcd = bid & 7, loc = bid >> 3;         // 8 XCDs x 27 M-tiles
    int m0 = loc * 256, n0 = xcd * 320;

    int wm = (wave & 3) << 6, wn = (wave >> 2) * 160;  // 4M x 2N waves, 64x160/wave
    int r32 = lane & 31, hi2 = lane >> 5;
    // common fragment-read base: slot(row>>4)*1024 + hi2*256 + (row&15)*16
    int rb  = (r32 >> 4) * 1024 + hi2 * 256 + (r32 & 15) * 16;
    int awb = (wm >> 4) * 1024 + rb;
    int bwb = (wn >> 4) * 1024 + rb;

    // 9 stage slots per wave: gid = wave*9+s over 72 total.
    // gid 0-15: Ah 16-row slots; 16-31: Al; 32-51: Bh; 52-71: Bl.
    // chunk-major staging: lane stages row (lane&15), k-chunk (lane>>4).
    int lrow = lane & 15, lchk = lane >> 4;
    const unsigned short* sp[9];
    int so[9];
    #pragma unroll
    for (int s = 0; s < 9; ++s) {
        int gid = wave * 9 + s;
        const unsigned short* base;
        int row0, ldso;
        if (gid < 16)      { base = Ah; row0 = m0 + gid * 16;        ldso = gid * 1024; }
        else if (gid < 32) { base = Al; row0 = m0 + (gid - 16) * 16; ldso = 16384 + (gid - 16) * 1024; }
        else if (gid < 52) { base = Bh; row0 = n0 + (gid - 32) * 16; ldso = SB_BH + (gid - 32) * 1024; }
        else               { base = Bl; row0 = n0 + (gid - 52) * 16; ldso = SB_BH + 20480 + (gid - 52) * 1024; }
        sp[s] = base + (size_t)(row0 + lrow) * KD + lchk * 8;
        so[s] = ldso;
    }

    f32x16 acc[2][5] = {};                     // 2 m-frags x 5 n-frags of 32x32

    char* CB = sm;                             // compute buffer
    char* NB = sm + BUFSZ;                     // staging buffer (next tile)

    #define STAGE(DST, s, koff) __builtin_amdgcn_global_load_lds( \
        (const __attribute__((address_space(1))) unsigned int*)(sp[s] + (koff)), \
        (__attribute__((address_space(3))) unsigned int*)((DST) + so[s]), 16, 0, 0)
    #define ARD(hl, mf, ks) (*(const bf16x8*)(CB + (hl) * 16384 + awb + (mf) * 2048 + (ks) * 512))
    #define BRD(hl, nf, ks) (*(const bf16x8*)(CB + SB_BH + (hl) * 20480 + bwb + (nf) * 2048 + (ks) * 512))
    #define TRIP(mf, nf, xh, xl, yh, yl) \
        acc[mf][nf] = __builtin_amdgcn_mfma_f32_32x32x16_bf16(xh, yh, acc[mf][nf], 0, 0, 0); \
        acc[mf][nf] = __builtin_amdgcn_mfma_f32_32x32x16_bf16(xh, yl, acc[mf][nf], 0, 0, 0); \
        acc[mf][nf] = __builtin_amdgcn_mfma_f32_32x32x16_bf16(xl, yh, acc[mf][nf], 0, 0, 0);
    #define SB __builtin_amdgcn_sched_barrier(0)

    // prologue: stage tile 0 into CB; __syncthreads drains vmcnt.
    #pragma unroll
    for (int s = 0; s < 9; ++s) STAGE(CB, s, 0);
    __syncthreads();

    for (int t = 0; t < 24; ++t) {             // K = 768 = 24 tiles of 32
        int kn = (t + 1) * 32;
        bool stg = (t < 23);
        bf16x8 a0h, a0l, a1h, a1l, bxh, bxl, byh, byl;

        // ===== ks = 0 =====
        a0h = ARD(0, 0, 0); a0l = ARD(1, 0, 0);
        a1h = ARD(0, 1, 0); a1l = ARD(1, 1, 0);
        bxh = BRD(0, 0, 0); bxl = BRD(1, 0, 0);
        byh = BRD(0, 1, 0); byl = BRD(1, 1, 0);
        if (stg) {
            #pragma unroll
            for (int s = 0; s < 9; ++s) STAGE(NB, s, kn);
        }
        SB;
        __builtin_amdgcn_s_setprio(1);
        TRIP(0, 0, a0h, a0l, bxh, bxl)
        TRIP(0, 1, a0h, a0l, byh, byl)
        TRIP(1, 0, a1h, a1l, bxh, bxl)
        TRIP(1, 1, a1h, a1l, byh, byl)
        __builtin_amdgcn_s_setprio(0);
        SB;
        bxh = BRD(0, 2, 0); bxl = BRD(1, 2, 0);
        byh = BRD(0, 3, 0); byl = BRD(1, 3, 0);
        SB;
        __builtin_amdgcn_s_setprio(1);
        TRIP(0, 2, a0h, a0l, bxh, bxl)
        TRIP(0, 3, a0h, a0l, byh, byl)
        TRIP(1, 2, a1h, a1l, bxh, bxl)
        TRIP(1, 3, a1h, a1l, byh, byl)
        __builtin_amdgcn_s_setprio(0);
        SB;
        bxh = BRD(0, 4, 0); bxl = BRD(1, 4, 0);
        SB;
        __builtin_amdgcn_s_setprio(1);
        TRIP(0, 4, a0h, a0l, bxh, bxl)
        TRIP(1, 4, a1h, a1l, bxh, bxl)
        __builtin_amdgcn_s_setprio(0);
        SB;

        // ===== ks = 1 =====
        a0h = ARD(0, 0, 1); a0l = ARD(1, 0, 1);
        a1h = ARD(0, 1, 1); a1l = ARD(1, 1, 1);
        bxh = BRD(0, 0, 1); bxl = BRD(1, 0, 1);
        byh = BRD(0, 1, 1); byl = BRD(1, 1, 1);
        SB;
        __builtin_amdgcn_s_setprio(1);
        TRIP(0, 0, a0h, a0l, bxh, bxl)
        TRIP(0, 1, a0h, a0l, byh, byl)
        TRIP(1, 0, a1h, a1l, bxh, bxl)
        TRIP(1, 1, a1h, a1l, byh, byl)
        __builtin_amdgcn_s_setprio(0);
        SB;
        bxh = BRD(0, 2, 1); bxl = BRD(1, 2, 1);
        byh = BRD(0, 3, 1); byl = BRD(1, 3, 1);
        SB;
        __builtin_amdgcn_s_setprio(1);
        TRIP(0, 2, a0h, a0l, bxh, bxl)
        TRIP(0, 3, a0h, a0l, byh, byl)
        TRIP(1, 2, a1h, a1l, bxh, bxl)
        TRIP(1, 3, a1h, a1l, byh, byl)
        __builtin_amdgcn_s_setprio(0);
        SB;
        bxh = BRD(0, 4, 1); bxl = BRD(1, 4, 1);
        SB;
        __builtin_amdgcn_s_setprio(1);
        TRIP(0, 4, a0h, a0l, bxh, bxl)
        TRIP(1, 4, a1h, a1l, bxh, bxl)
        __builtin_amdgcn_s_setprio(0);

        // tile boundary: drains vmcnt (next-tile stages resident) and gates the
        // buffer swap (all waves done reading CB).
        __syncthreads();
        char* tmp = CB; CB = NB; NB = tmp;
    }

    // epilogue: C/D layout of 32x32: col(n)=lane&31, row(m)=(reg&3)+8*(reg>>2)+4*(lane>>5)
    #pragma unroll
    for (int mf = 0; mf < 2; ++mf)
        #pragma unroll
        for (int nf = 0; nf < 5; ++nf) {
            int n = n0 + wn + nf * 32 + r32;
            size_t rowb = (size_t)n * MG + m0 + wm + mf * 32 + 4 * hi2;
            #pragma unroll
            for (int g = 0; g < 4; ++g) {
                f32x4 v = { acc[mf][nf][g * 4 + 0], acc[mf][nf][g * 4 + 1],
                            acc[mf][nf][g * 4 + 2], acc[mf][nf][g * 4 + 3] };
                *(f32x4*)(Yt + rowb + 8 * g) = v;
            }
        }
    #undef STAGE
    #undef ARD
    #undef BRD
    #undef TRIP
    #undef SB
}

// ---------------- gather taps -> hm (masked rows) + GN partial sums (active pixels only) ----------------
__global__ __launch_bounds__(256) void k_gather(const float* __restrict__ Yt,
                                                const int* __restrict__ qidx,
                                                const int* __restrict__ apix,
                                                float* __restrict__ hm,
                                                double* __restrict__ part) {
    __shared__ double red1[256 * 4], red2[256 * 4];
    int tid = threadIdx.x;
    int wave = tid >> 6, lane = tid & 63;
    double a1[3] = {0, 0, 0}, a2[3] = {0, 0, 0};
    int gs[3];
    #pragma unroll
    for (int s = 0; s < 3; ++s) gs[s] = (64 * s + lane) / 48;

    for (int it = 0; it < 8; ++it) {
        int p = blockIdx.x * 32 + wave * 8 + it;   // wave-uniform pixel
        if (!apix[p]) continue;
        int y = p >> 7, x = p & 127;
        float4 hv[3] = {};
        #pragma unroll
        for (int tap = 0; tap < 9; ++tap) {
            int i = y + tap / 3 - 1, j = x + tap % 3 - 1;
            if ((unsigned)i < 128u && (unsigned)j < 128u) {
                int q = qidx[i * NPIX + j];
                if (q >= 0) {
                    const float* yr = Yt + (size_t)q * MG + tap * 768 + lane * 4;
                    #pragma unroll
                    for (int s = 0; s < 3; ++s) {
                        float4 v = *(const float4*)(yr + s * 256);
                        hv[s].x += v.x; hv[s].y += v.y; hv[s].z += v.z; hv[s].w += v.w;
                    }
                }
            }
        }
        int qp = qidx[p];
        if (qp >= 0) {
            #pragma unroll
            for (int s = 0; s < 3; ++s)
                *(float4*)(hm + (size_t)qp * KD + s * 256 + lane * 4) = hv[s];
        }
        #pragma unroll
        for (int s = 0; s < 3; ++s) {
            a1[s] += (double)hv[s].x + (double)hv[s].y + (double)hv[s].z + (double)hv[s].w;
            a2[s] += (double)hv[s].x * hv[s].x + (double)hv[s].y * hv[s].y +
                     (double)hv[s].z * hv[s].z + (double)hv[s].w * hv[s].w;
        }
    }
    #pragma unroll
    for (int g = 0; g < 4; ++g) { red1[tid * 4 + g] = 0.0; red2[tid * 4 + g] = 0.0; }
    #pragma unroll
    for (int s = 0; s < 3; ++s) { red1[tid * 4 + gs[s]] = a1[s]; red2[tid * 4 + gs[s]] = a2[s]; }
    __syncthreads();
    if (tid < 8) {
        int g = tid & 3;
        double s = 0.0;
        if (tid < 4) { for (int i = 0; i < 256; ++i) s += red1[i * 4 + g]; }
        else         { for (int i = 0; i < 256; ++i) s += red2[i * 4 + g]; }
        atomicAdd(&part[tid], s);
    }
}

// ---------------- fused GN + ReLU + 1x1 conv + sigmoid at mask positions ----------------
__global__ void k_score(const float* __restrict__ hm, const double* __restrict__ part,
                        const float* __restrict__ gamma, const float* __restrict__ beta,
                        const float* __restrict__ w2, const float* __restrict__ b2,
                        float* __restrict__ scores) {
    int q = blockIdx.x * 4 + (threadIdx.x >> 6);
    int lane = threadIdx.x & 63;
    if (q >= MASKM) return;
    float mu[4], rs[4];
    const double cnt = 192.0 * 16384.0;
    #pragma unroll
    for (int g = 0; g < 4; ++g) {
        double m = part[g] / cnt;
        double v = part[4 + g] / cnt - m * m;
        mu[g] = (float)m;
        rs[g] = (float)(1.0 / sqrt(v + 1e-5));
    }
    const float* hp = hm + (size_t)q * KD;
    float s = 0.f;
    for (int c = lane; c < KD; c += 64) {
        int g = c / 192;
        float v = (hp[c] - mu[g]) * rs[g] * gamma[c] + beta[c];
        s += fmaxf(v, 0.f) * w2[c];
    }
    for (int o = 32; o; o >>= 1) s += __shfl_down(s, o, 64);
    if (lane == 0) scores[q] = 1.f / (1.f + expf(-(s + b2[0])));
}

// ---------------- greedy NMS via 5-round iterative argmax (== stable sorted greedy) ----------------
__device__ __forceinline__ unsigned long long shfl_down_u64(unsigned long long v, int o) {
    unsigned lo = (unsigned)v, hi = (unsigned)(v >> 32);
    lo = __shfl_down(lo, o, 64);
    hi = __shfl_down(hi, o, 64);
    return ((unsigned long long)hi << 32) | lo;
}

__global__ void k_nms(const float* __restrict__ scores, const int* __restrict__ qi,
                      const int* __restrict__ qj, const int* __restrict__ durp,
                      float* __restrict__ out) {
    __shared__ unsigned long long key[MASKM];
    __shared__ float ss[MASKM], ee[MASKM];
    __shared__ unsigned char st[MASKM];     // 0 free, 1 suppressed, 2 kept, 3 picked-fallback
    __shared__ unsigned long long wm0[16], wm1[16];
    __shared__ int sh_keeper, keepq[5];
    __shared__ float sh_s0, sh_e0;
    int t = threadIdx.x;                    // 1024
    float delta = (float)(*durp) / 128.f;
    for (int i = t; i < MASKM; i += 1024) {
        unsigned sb = __float_as_uint(scores[i]);            // scores > 0: bits monotonic
        key[i] = ((unsigned long long)sb << 32) | (unsigned)(4095 - i);  // tie: lower q wins
        ss[i] = qi[i] * delta;
        ee[i] = (qj[i] + 1) * delta;
        st[i] = 0;
    }
    __syncthreads();
    for (int round = 0; round < 5; ++round) {
        unsigned long long b0 = 0, b1 = 0;
        for (int i = t; i < MASKM; i += 1024) {
            unsigned char s = st[i];
            unsigned long long k = key[i];
            if (s == 0) { if (k > b0) b0 = k; }
            else if (s == 1) { if (k > b1) b1 = k; }
        }
        for (int o = 32; o; o >>= 1) {
            unsigned long long u0 = shfl_down_u64(b0, o), u1 = shfl_down_u64(b1, o);
            if (u0 > b0) b0 = u0;
            if (u1 > b1) b1 = u1;
        }
        if ((t & 63) == 0) { wm0[t >> 6] = b0; wm1[t >> 6] = b1; }
        __syncthreads();
        if (t == 0) {
            unsigned long long B0 = 0, B1 = 0;
            for (int w = 0; w < 16; ++w) {
                if (wm0[w] > B0) B0 = wm0[w];
                if (wm1[w] > B1) B1 = wm1[w];
            }
            int keeper = (B0 != 0);
            unsigned long long B = keeper ? B0 : B1;
            int q = 4095 - (int)(B & 0xFFFFFFFFull);
            st[q] = keeper ? 2 : 3;
            sh_keeper = keeper;
            sh_s0 = ss[q]; sh_e0 = ee[q];
            keepq[round] = q;
        }
        __syncthreads();
        if (sh_keeper) {
            float s0 = sh_s0, e0 = sh_e0;
            for (int i = t; i < MASKM; i += 1024) {
                if (st[i] == 0) {
                    float inter = fminf(ee[i], e0) - fmaxf(ss[i], s0);
                    if (inter > 0.f) {
                        float uni = fmaxf(ee[i], e0) - fminf(ss[i], s0);
                        if (inter / uni > 0.5f) st[i] = 1;
                    }
                }
            }
        }
        __syncthreads();
    }
    if (t < 5) { out[t * 2] = ss[keepq[t]]; out[t * 2 + 1] = ee[keepq[t]]; }
}

// ---------------- launch ----------------
extern "C" void kernel_launch(void* const* d_in, const int* in_sizes, int n_in,
                              void* d_out, int out_size, void* d_ws, size_t ws_size,
                              hipStream_t stream) {
    const float* fea   = (const float*)d_in[0];
    const int*   dur   = (const int*)d_in[1];
    const float* w1    = (const float*)d_in[2];
    const float* gamma = (const float*)d_in[3];
    const float* beta  = (const float*)d_in[4];
    const float* w2    = (const float*)d_in[5];
    const float* b2    = (const float*)d_in[6];
    float* out = (float*)d_out;

    char* ws = (char*)d_ws;
    int*    qi     = (int*)(ws + OFF_QI);
    int*    qj     = (int*)(ws + OFF_QJ);
    int*    qidx   = (int*)(ws + OFF_QIDX);
    int*    apix   = (int*)(ws + OFF_APIX);
    double* part   = (double*)(ws + OFF_PART);
    float*  scores = (float*)(ws + OFF_SC);
    float*  hm     = (float*)(ws + OFF_HM);
    unsigned short* AhU = (unsigned short*)(ws + OFF_AH);
    unsigned short* AlU = (unsigned short*)(ws + OFF_AL);
    unsigned short* BhU = (unsigned short*)(ws + OFF_BH);
    unsigned short* BlU = (unsigned short*)(ws + OFF_BL);
    float*  Yt     = (float*)(ws + OFF_YT);
    float*  X      = (float*)(ws + OFF_X);   // aliases Yt head

    // allow 144 KB dynamic LDS for k_gemm (one-time host-side attribute)
    static bool gemm_attr_set = false;
    if (!gemm_attr_set) {
        hipFuncSetAttribute((const void*)k_gemm,
                            hipFuncAttributeMaxDynamicSharedMemorySize, 2 * BUFSZ);
        gemm_attr_set = true;
    }

    k_fill<<<64, 256, 0, stream>>>(qi, qj, qidx, apix, part);
    k_buildX<<<768, 128, 0, stream>>>(fea, qi, qj, X);
    k_prepA<<<dim3(12, 12), 256, 0, stream>>>(w1, AhU, AlU);
    k_trans<<<dim3(40, 12), 256, 0, stream>>>(X, NPAD, BhU, BlU);
    k_gemm<<<dim3(216), 512, 2 * BUFSZ, stream>>>(AhU, AlU, BhU, BlU, Yt);
    k_gather<<<512, 256, 0, stream>>>(Yt, qidx, apix, hm, part);
    k_score<<<637, 256, 0, stream>>>(hm, part, gamma, beta, w2, b2, scores);
    k_nms<<<1, 1024, 0, stream>>>(scores, qi, qj, dur, out);
}